// Round 1
// baseline (180.394 us; speedup 1.0000x reference)
//
#include <hip/hip_runtime.h>
#include <hip/hip_bf16.h>

#define T_TOK 8192
#define DIM   1024
#define NEXP  8

typedef __bf16 bf16_t;
typedef bf16_t bf16x8 __attribute__((ext_vector_type(8)));
typedef bf16_t bf16x4 __attribute__((ext_vector_type(4)));
typedef float  f32x4  __attribute__((ext_vector_type(4)));

// ---- workspace layout (bytes) ----
#define WS_CNT    0                       // 64 ints  (pair counters)
#define WS_NTILE  256                     // 1 int
#define WS_DESC   512                     // 512 ints (tile descriptors)
#define WS_LIST   4096                    // 64 * 8192 ints = 2 MB
#define WS_XBF    (4096 + 64*T_TOK*4)     // T*D bf16 = 16 MB
#define WS_WT     (WS_XBF + T_TOK*DIM*2)  // 8*D*D bf16 = 16 MB
// total ~35.7 MB

// ------------------------------------------------------------------
// Kernel 1: WT[e][f][d] = bf16(expert_w[e][d][f])  (transpose+convert)
// ------------------------------------------------------------------
__global__ __launch_bounds__(256) void transpose_w(const float* __restrict__ ew,
                                                   bf16_t* __restrict__ wt) {
    __shared__ float tile[64][65];
    int e  = blockIdx.z;
    int d0 = blockIdx.y * 64;
    int f0 = blockIdx.x * 64;
    int tid = threadIdx.x;
    const float* src = ew + ((size_t)e * DIM + d0) * DIM + f0;
    int fl = (tid & 15) * 4;
    int dl = tid >> 4;                       // 0..15
    for (int i = 0; i < 4; i++) {
        int d = dl + i * 16;
        float4 v = *(const float4*)(src + (size_t)d * DIM + fl);
        tile[d][fl + 0] = v.x; tile[d][fl + 1] = v.y;
        tile[d][fl + 2] = v.z; tile[d][fl + 3] = v.w;
    }
    __syncthreads();
    bf16_t* dst = wt + ((size_t)e * DIM + f0) * DIM + d0;
    int dl2 = (tid & 15) * 4;
    int fl2 = tid >> 4;
    for (int i = 0; i < 4; i++) {
        int f = fl2 + i * 16;
        bf16x4 v;
        v[0] = (bf16_t)tile[dl2 + 0][f];
        v[1] = (bf16_t)tile[dl2 + 1][f];
        v[2] = (bf16_t)tile[dl2 + 2][f];
        v[3] = (bf16_t)tile[dl2 + 3][f];
        *(bf16x4*)(dst + (size_t)f * DIM + dl2) = v;
    }
}

// ------------------------------------------------------------------
// Kernel 2: routing (logits -> top2 -> pair bucket) + x -> bf16 copy
// one wave per token
// ------------------------------------------------------------------
__global__ __launch_bounds__(256) void route(const float* __restrict__ x,
                                             const float* __restrict__ gw,
                                             const float* __restrict__ gb,
                                             bf16_t* __restrict__ xbf,
                                             int* __restrict__ cnt,
                                             int* __restrict__ list) {
    int wid  = threadIdx.x >> 6;
    int lane = threadIdx.x & 63;
    int t    = blockIdx.x * 4 + wid;
    const float* xr = x + (size_t)t * DIM;
    float acc[NEXP] = {};
    for (int j = 0; j < 4; j++) {
        int d = j * 256 + lane * 4;
        float4 v = *(const float4*)(xr + d);
        bf16x4 b;
        b[0] = (bf16_t)v.x; b[1] = (bf16_t)v.y;
        b[2] = (bf16_t)v.z; b[3] = (bf16_t)v.w;
        *(bf16x4*)(xbf + (size_t)t * DIM + d) = b;
        float vv[4] = {v.x, v.y, v.z, v.w};
        for (int i = 0; i < 4; i++) {
            float4 g0 = *(const float4*)(gw + (size_t)(d + i) * NEXP);
            float4 g1 = *(const float4*)(gw + (size_t)(d + i) * NEXP + 4);
            acc[0] += vv[i] * g0.x; acc[1] += vv[i] * g0.y;
            acc[2] += vv[i] * g0.z; acc[3] += vv[i] * g0.w;
            acc[4] += vv[i] * g1.x; acc[5] += vv[i] * g1.y;
            acc[6] += vv[i] * g1.z; acc[7] += vv[i] * g1.w;
        }
    }
    for (int off = 32; off >= 1; off >>= 1)
        for (int e = 0; e < NEXP; e++)
            acc[e] += __shfl_xor(acc[e], off, 64);
    if (lane == 0) {
        float logit[NEXP];
        for (int e = 0; e < NEXP; e++) logit[e] = acc[e] + gb[e];
        int b1 = 0; float best = logit[0];
        for (int e = 1; e < NEXP; e++) if (logit[e] > best) { best = logit[e]; b1 = e; }
        int b2 = -1; float best2 = -3.0e38f;
        for (int e = 0; e < NEXP; e++) {
            if (e == b1) continue;
            if (logit[e] > best2) { best2 = logit[e]; b2 = e; }
        }
        int a = min(b1, b2), bb = max(b1, b2);
        int p = a * 8 + bb;
        int pos = atomicAdd(&cnt[p], 1);
        list[p * T_TOK + pos] = t;
    }
}

// ------------------------------------------------------------------
// Kernel 3: build m-tile work queue (one wave)
// ------------------------------------------------------------------
__global__ void prep(const int* __restrict__ cnt, int* __restrict__ ntile,
                     int* __restrict__ desc) {
    int lane = threadIdx.x;   // 0..63
    int c  = cnt[lane];
    int tp = (c + 63) >> 6;
    int pre = 0, tot = 0;
    for (int i = 0; i < 64; i++) {
        int v = __shfl(tp, i, 64);
        if (i < lane) pre += v;
        tot += v;
    }
    for (int j = 0; j < tp; j++)
        desc[pre + j] = lane | ((j * 64) << 8);
    if (lane == 0) *ntile = tot;
}

// ------------------------------------------------------------------
// Kernel 4: grouped GEMM over pair buckets.
// C[64x256] per block, BK=64, 4 waves (each 64x64), 16x16x32 bf16 MFMA.
// B-tile = WT[e1] + WT[e2] summed during staging (fp32 add).
// XOR-swizzled LDS to kill ds_read_b128 bank conflicts.
// ------------------------------------------------------------------
#define BM 64
#define BN 256
#define BK 64

__device__ __forceinline__ int swz(int r, int k) {
    return ((r * BK + k) * 2) ^ ((r & 7) << 4);
}

__global__ __launch_bounds__(256) void moe_gemm(const bf16_t* __restrict__ xbf,
                                                const bf16_t* __restrict__ wt,
                                                const int* __restrict__ cnt,
                                                const int* __restrict__ ntile_p,
                                                const int* __restrict__ desc,
                                                const int* __restrict__ list,
                                                float* __restrict__ out) {
    __shared__ __align__(16) bf16_t As[BM * BK];
    __shared__ __align__(16) bf16_t Bs[BN * BK];
    __shared__ int toks[BM];
    int tid  = threadIdx.x;
    int lane = tid & 63;
    int wv   = tid >> 6;
    int nwork = (*ntile_p) * (DIM / BN);
    for (int w = blockIdx.x; w < nwork; w += gridDim.x) {
        __syncthreads();   // protect toks/LDS from previous item's readers
        int dsc = desc[w >> 2];
        int nb  = w & 3;
        int p   = dsc & 63;
        int m0  = dsc >> 8;
        int e1  = p >> 3, e2 = p & 7;
        int cp  = cnt[p];
        int valid = min(BM, cp - m0);
        if (tid < BM) toks[tid] = list[p * T_TOK + m0 + min(tid, valid - 1)];
        __syncthreads();
        int n0 = nb * BN;
        f32x4 acc[4][4] = {};
        int r = tid >> 2, q = tid & 3;           // staging roles
        const bf16_t* wt1 = wt + (size_t)e1 * DIM * DIM;
        const bf16_t* wt2 = wt + (size_t)e2 * DIM * DIM;
        for (int k0 = 0; k0 < DIM; k0 += BK) {
            // ---- stage A (64 x 64 bf16) ----
            {
                const bf16_t* src = xbf + (size_t)toks[r] * DIM + k0 + q * 16;
                bf16x8 v0 = *(const bf16x8*)src;
                bf16x8 v1 = *(const bf16x8*)(src + 8);
                *(bf16x8*)((char*)As + swz(r, q * 16))     = v0;
                *(bf16x8*)((char*)As + swz(r, q * 16 + 8)) = v1;
            }
            // ---- stage B (256 x 64 bf16) = WT[e1]+WT[e2], [f][d] layout ----
            for (int fo = 0; fo < 4; fo++) {
                int f = fo * 64 + r;
                const bf16_t* s1 = wt1 + (size_t)(n0 + f) * DIM + k0 + q * 16;
                const bf16_t* s2 = wt2 + (size_t)(n0 + f) * DIM + k0 + q * 16;
                bf16x8 u0 = *(const bf16x8*)s1;
                bf16x8 u1 = *(const bf16x8*)(s1 + 8);
                bf16x8 w0 = *(const bf16x8*)s2;
                bf16x8 w1 = *(const bf16x8*)(s2 + 8);
                bf16x8 o0, o1;
                for (int i = 0; i < 8; i++) {
                    o0[i] = (bf16_t)((float)u0[i] + (float)w0[i]);
                    o1[i] = (bf16_t)((float)u1[i] + (float)w1[i]);
                }
                *(bf16x8*)((char*)Bs + swz(f, q * 16))     = o0;
                *(bf16x8*)((char*)Bs + swz(f, q * 16 + 8)) = o1;
            }
            __syncthreads();
            // ---- fragments + MFMA ----
            int lr = lane & 15;
            int lk = (lane >> 4) * 8;
            bf16x8 af[2][4], bfr[2][4];
            for (int kk = 0; kk < 2; kk++) {
                for (int mf = 0; mf < 4; mf++)
                    af[kk][mf] = *(const bf16x8*)((const char*)As +
                                   swz(mf * 16 + lr, kk * 32 + lk));
                for (int nf = 0; nf < 4; nf++)
                    bfr[kk][nf] = *(const bf16x8*)((const char*)Bs +
                                   swz(wv * 64 + nf * 16 + lr, kk * 32 + lk));
            }
            for (int kk = 0; kk < 2; kk++)
                for (int mf = 0; mf < 4; mf++)
                    for (int nf = 0; nf < 4; nf++)
                        acc[mf][nf] = __builtin_amdgcn_mfma_f32_16x16x32_bf16(
                            af[kk][mf], bfr[kk][nf], acc[mf][nf], 0, 0, 0);
            __syncthreads();
        }
        // ---- write C: row = (lane>>4)*4+reg, col = lane&15 (per 16x16 frag) ----
        int lr = lane & 15;
        for (int mf = 0; mf < 4; mf++) {
            for (int reg = 0; reg < 4; reg++) {
                int rl = mf * 16 + (lane >> 4) * 4 + reg;
                if (rl < valid) {
                    size_t trow = (size_t)toks[rl] * DIM;
                    for (int nf = 0; nf < 4; nf++)
                        out[trow + n0 + wv * 64 + nf * 16 + lr] = acc[mf][nf][reg];
                }
            }
        }
    }
}

// ------------------------------------------------------------------
extern "C" void kernel_launch(void* const* d_in, const int* in_sizes, int n_in,
                              void* d_out, int out_size, void* d_ws, size_t ws_size,
                              hipStream_t stream) {
    const float* x  = (const float*)d_in[0];
    const float* gw = (const float*)d_in[1];
    const float* gb = (const float*)d_in[2];
    const float* ew = (const float*)d_in[3];
    float* out = (float*)d_out;
    char* ws = (char*)d_ws;
    int*    cnt   = (int*)(ws + WS_CNT);
    int*    ntile = (int*)(ws + WS_NTILE);
    int*    desc  = (int*)(ws + WS_DESC);
    int*    list  = (int*)(ws + WS_LIST);
    bf16_t* xbf   = (bf16_t*)(ws + WS_XBF);
    bf16_t* wt    = (bf16_t*)(ws + WS_WT);

    hipMemsetAsync(d_ws, 0, 4096, stream);
    transpose_w<<<dim3(16, 16, 8), 256, 0, stream>>>(ew, wt);
    route<<<dim3(2048), 256, 0, stream>>>(x, gw, gb, xbf, cnt, list);
    prep<<<dim3(1), 64, 0, stream>>>(cnt, ntile, desc);
    moe_gemm<<<dim3(1024), 256, 0, stream>>>(xbf, wt, cnt, ntile, desc, list, out);
}

// Round 2
// 154.822 us; speedup vs baseline: 1.1652x; 1.1652x over previous
//
#include <hip/hip_runtime.h>
#include <hip/hip_bf16.h>
#include <stdint.h>

#define T_TOK 8192
#define DIM   1024
#define NEXP  8
#define BM    128
#define BN    128
#define BK    64

typedef __bf16 bf16_t;
typedef bf16_t bf16x8 __attribute__((ext_vector_type(8)));
typedef bf16_t bf16x4 __attribute__((ext_vector_type(4)));
typedef float  f32x4  __attribute__((ext_vector_type(4)));

// ---- workspace layout (bytes) ----
#define WS_CNT    0                  // 64 ints (pair counters)
#define WS_NTILE  256                // 1 int
#define WS_DESC   512                // tile descriptors (<=128 used)
#define WS_LIST   4096               // 64 * 8192 ints = 2 MB
#define WS_XBF    (4u << 20)         // T*D bf16 = 16 MB
#define WS_W2     (20u << 20)        // WSUM (28*2MB=56MB) or fallback WT (16MB)
#define WS_NEED_PSUM ((size_t)76 << 20)

// pair index tables: pk -> (a,b), a<b
__device__ const int d_PA[28] = {0,0,0,0,0,0,0,1,1,1,1,1,1,2,2,2,2,2,3,3,3,3,4,4,4,5,5,6};
__device__ const int d_PB[28] = {1,2,3,4,5,6,7,2,3,4,5,6,7,3,4,5,6,7,4,5,6,7,5,6,7,6,7,7};

// async 16B global -> LDS (lds dest must be wave-uniform base; HW adds lane*16)
__device__ __forceinline__ void gload16(const void* g, void* l) {
    __builtin_amdgcn_global_load_lds(
        (const __attribute__((address_space(1))) unsigned int*)g,
        (__attribute__((address_space(3))) unsigned int*)l, 16, 0, 0);
}

// swizzled byte offset within a [rows][BK] bf16 tile; k in elements (16B-aligned use)
__device__ __forceinline__ int swz(int r, int k) {
    return ((r * BK + k) * 2) ^ ((r & 7) << 4);
}

// ------------------------------------------------------------------
// sumw: WSUM[pk][f][d] = bf16(ew[a][d][f] + ew[b][d][f])   (28 pairs)
// ------------------------------------------------------------------
__global__ __launch_bounds__(256) void sumw(const float* __restrict__ ew,
                                            bf16_t* __restrict__ wsum) {
    __shared__ float tile[64][65];
    int pk = blockIdx.z;
    int a = d_PA[pk], b = d_PB[pk];
    int d0 = blockIdx.y * 64;
    int f0 = blockIdx.x * 64;
    int tid = threadIdx.x;
    const float* s1 = ew + ((size_t)a * DIM + d0) * DIM + f0;
    const float* s2 = ew + ((size_t)b * DIM + d0) * DIM + f0;
    int fl = (tid & 15) * 4;
    int dl = tid >> 4;
    #pragma unroll
    for (int i = 0; i < 4; i++) {
        int d = dl + i * 16;
        float4 u = *(const float4*)(s1 + (size_t)d * DIM + fl);
        float4 v = *(const float4*)(s2 + (size_t)d * DIM + fl);
        tile[d][fl + 0] = u.x + v.x; tile[d][fl + 1] = u.y + v.y;
        tile[d][fl + 2] = u.z + v.z; tile[d][fl + 3] = u.w + v.w;
    }
    __syncthreads();
    bf16_t* dst = wsum + ((size_t)pk * DIM + f0) * DIM + d0;
    int dl2 = (tid & 15) * 4;
    int fl2 = tid >> 4;
    #pragma unroll
    for (int i = 0; i < 4; i++) {
        int f = fl2 + i * 16;
        bf16x4 o;
        o[0] = (bf16_t)tile[dl2 + 0][f];
        o[1] = (bf16_t)tile[dl2 + 1][f];
        o[2] = (bf16_t)tile[dl2 + 2][f];
        o[3] = (bf16_t)tile[dl2 + 3][f];
        *(bf16x4*)(dst + (size_t)f * DIM + dl2) = o;
    }
}

// ------------------------------------------------------------------
// fallback: WT[e][f][d] = bf16(expert_w[e][d][f])
// ------------------------------------------------------------------
__global__ __launch_bounds__(256) void transpose_w(const float* __restrict__ ew,
                                                   bf16_t* __restrict__ wt) {
    __shared__ float tile[64][65];
    int e  = blockIdx.z;
    int d0 = blockIdx.y * 64;
    int f0 = blockIdx.x * 64;
    int tid = threadIdx.x;
    const float* src = ew + ((size_t)e * DIM + d0) * DIM + f0;
    int fl = (tid & 15) * 4;
    int dl = tid >> 4;
    #pragma unroll
    for (int i = 0; i < 4; i++) {
        int d = dl + i * 16;
        float4 v = *(const float4*)(src + (size_t)d * DIM + fl);
        tile[d][fl + 0] = v.x; tile[d][fl + 1] = v.y;
        tile[d][fl + 2] = v.z; tile[d][fl + 3] = v.w;
    }
    __syncthreads();
    bf16_t* dst = wt + ((size_t)e * DIM + f0) * DIM + d0;
    int dl2 = (tid & 15) * 4;
    int fl2 = tid >> 4;
    #pragma unroll
    for (int i = 0; i < 4; i++) {
        int f = fl2 + i * 16;
        bf16x4 v;
        v[0] = (bf16_t)tile[dl2 + 0][f];
        v[1] = (bf16_t)tile[dl2 + 1][f];
        v[2] = (bf16_t)tile[dl2 + 2][f];
        v[3] = (bf16_t)tile[dl2 + 3][f];
        *(bf16x4*)(dst + (size_t)f * DIM + dl2) = v;
    }
}

// ------------------------------------------------------------------
// route: logits -> top2 -> pair bucket; also x -> bf16 copy
// ------------------------------------------------------------------
__global__ __launch_bounds__(256) void route(const float* __restrict__ x,
                                             const float* __restrict__ gw,
                                             const float* __restrict__ gb,
                                             bf16_t* __restrict__ xbf,
                                             int* __restrict__ cnt,
                                             int* __restrict__ list) {
    int wid  = threadIdx.x >> 6;
    int lane = threadIdx.x & 63;
    int t    = blockIdx.x * 4 + wid;
    const float* xr = x + (size_t)t * DIM;
    float acc[NEXP] = {};
    for (int j = 0; j < 4; j++) {
        int d = j * 256 + lane * 4;
        float4 v = *(const float4*)(xr + d);
        bf16x4 b;
        b[0] = (bf16_t)v.x; b[1] = (bf16_t)v.y;
        b[2] = (bf16_t)v.z; b[3] = (bf16_t)v.w;
        *(bf16x4*)(xbf + (size_t)t * DIM + d) = b;
        float vv[4] = {v.x, v.y, v.z, v.w};
        #pragma unroll
        for (int i = 0; i < 4; i++) {
            float4 g0 = *(const float4*)(gw + (size_t)(d + i) * NEXP);
            float4 g1 = *(const float4*)(gw + (size_t)(d + i) * NEXP + 4);
            acc[0] += vv[i] * g0.x; acc[1] += vv[i] * g0.y;
            acc[2] += vv[i] * g0.z; acc[3] += vv[i] * g0.w;
            acc[4] += vv[i] * g1.x; acc[5] += vv[i] * g1.y;
            acc[6] += vv[i] * g1.z; acc[7] += vv[i] * g1.w;
        }
    }
    for (int off = 32; off >= 1; off >>= 1)
        #pragma unroll
        for (int e = 0; e < NEXP; e++)
            acc[e] += __shfl_xor(acc[e], off, 64);
    if (lane == 0) {
        float logit[NEXP];
        for (int e = 0; e < NEXP; e++) logit[e] = acc[e] + gb[e];
        int b1 = 0; float best = logit[0];
        for (int e = 1; e < NEXP; e++) if (logit[e] > best) { best = logit[e]; b1 = e; }
        int b2 = -1; float best2 = -3.0e38f;
        for (int e = 0; e < NEXP; e++) {
            if (e == b1) continue;
            if (logit[e] > best2) { best2 = logit[e]; b2 = e; }
        }
        int a = min(b1, b2), bb = max(b1, b2);
        int p = a * 8 + bb;
        int pos = atomicAdd(&cnt[p], 1);
        list[p * T_TOK + pos] = t;
    }
}

// ------------------------------------------------------------------
// prep: build m-tile queue (one wave), BM=128 tiles
// ------------------------------------------------------------------
__global__ void prep(const int* __restrict__ cnt, int* __restrict__ ntile,
                     int* __restrict__ desc) {
    int lane = threadIdx.x;   // 0..63 = pair id
    int c  = cnt[lane];
    int tp = (c + BM - 1) >> 7;
    int pre = 0, tot = 0;
    for (int i = 0; i < 64; i++) {
        int v = __shfl(tp, i, 64);
        if (i < lane) pre += v;
        tot += v;
    }
    for (int j = 0; j < tp; j++)
        desc[pre + j] = lane | ((j * BM) << 8);
    if (lane == 0) *ntile = tot;
}

// ------------------------------------------------------------------
// grouped GEMM: C[128x128] per work item, BK=64, 4 waves (2x2, 64x64 each).
// A gathered by token via global_load_lds with pre-swizzled source;
// B from WSUM[pk] (PSUM=1) via global_load_lds, or dual-WT reg-staged (PSUM=0).
// ------------------------------------------------------------------
template <int PSUM>
__global__ __launch_bounds__(256) void moe_gemm(const bf16_t* __restrict__ xbf,
                                                const bf16_t* __restrict__ wsrc,
                                                const int* __restrict__ cnt,
                                                const int* __restrict__ ntile_p,
                                                const int* __restrict__ desc,
                                                const int* __restrict__ list,
                                                float* __restrict__ out) {
    __shared__ __align__(16) bf16_t As[BM * BK];
    __shared__ __align__(16) bf16_t Bs[BN * BK];
    __shared__ int toks[BM];
    int tid  = threadIdx.x;
    int lane = tid & 63;
    int wv   = tid >> 6;
    int wm   = wv >> 1, wn = wv & 1;
    int nwork = (*ntile_p) * (DIM / BN);
    for (int w = blockIdx.x; w < nwork; w += gridDim.x) {
        __syncthreads();                     // protect toks/LDS from prev item
        int dsc = desc[w >> 3];
        int n0  = (w & 7) * BN;
        int p   = dsc & 63;
        int m0  = dsc >> 8;
        int e1  = p >> 3, e2 = p & 7;
        int cp  = cnt[p];
        int valid = min(BM, cp - m0);
        if (tid < BM) toks[tid] = list[p * T_TOK + m0 + min(tid, valid - 1)];
        __syncthreads();

        // A gather sources: chunk c = i*256+tid; row r=c>>3, lin chunk jl=c&7,
        // source chunk js = jl ^ (r&7)  (inverse swizzle, LDS dest stays linear)
        const bf16_t* asrc[4];
        #pragma unroll
        for (int i = 0; i < 4; i++) {
            int c = i * 256 + tid;
            int r = c >> 3, js = (c & 7) ^ (r & 7);
            asrc[i] = xbf + (size_t)toks[r] * DIM + js * 8;
        }
        const bf16_t* bsrc[4];
        const bf16_t *wt1 = nullptr, *wt2 = nullptr;
        if (PSUM) {
            int pk = e1 * 7 - (e1 * (e1 - 1)) / 2 + (e2 - e1 - 1);
            const bf16_t* bb = wsrc + (size_t)pk * DIM * DIM;
            #pragma unroll
            for (int i = 0; i < 4; i++) {
                int c = i * 256 + tid;
                int r = c >> 3, js = (c & 7) ^ (r & 7);
                bsrc[i] = bb + (size_t)(n0 + r) * DIM + js * 8;
            }
        } else {
            wt1 = wsrc + (size_t)e1 * DIM * DIM;
            wt2 = wsrc + (size_t)e2 * DIM * DIM;
        }

        f32x4 acc[4][4] = {};
        for (int k0 = 0; k0 < DIM; k0 += BK) {
            // ---- stage A (128x64) async ----
            #pragma unroll
            for (int i = 0; i < 4; i++)
                gload16(asrc[i] + k0, As + (size_t)(i * 256 + wv * 64) * 8);
            // ---- stage B (128x64) ----
            if (PSUM) {
                #pragma unroll
                for (int i = 0; i < 4; i++)
                    gload16(bsrc[i] + k0, Bs + (size_t)(i * 256 + wv * 64) * 8);
            } else {
                #pragma unroll
                for (int fo = 0; fo < 2; fo++) {
                    int f = fo * 64 + (tid >> 2), q = tid & 3;
                    const bf16_t* s1 = wt1 + (size_t)(n0 + f) * DIM + k0 + q * 16;
                    const bf16_t* s2 = wt2 + (size_t)(n0 + f) * DIM + k0 + q * 16;
                    bf16x8 u0 = *(const bf16x8*)s1;
                    bf16x8 u1 = *(const bf16x8*)(s1 + 8);
                    bf16x8 w0 = *(const bf16x8*)s2;
                    bf16x8 w1 = *(const bf16x8*)(s2 + 8);
                    bf16x8 o0, o1;
                    #pragma unroll
                    for (int i = 0; i < 8; i++) {
                        o0[i] = (bf16_t)((float)u0[i] + (float)w0[i]);
                        o1[i] = (bf16_t)((float)u1[i] + (float)w1[i]);
                    }
                    *(bf16x8*)((char*)Bs + swz(f, q * 16))     = o0;
                    *(bf16x8*)((char*)Bs + swz(f, q * 16 + 8)) = o1;
                }
            }
            __syncthreads();                 // drains vmcnt+lgkmcnt
            int lr = lane & 15;
            int lk = (lane >> 4) * 8;
            bf16x8 af[2][4], bfr[2][4];
            #pragma unroll
            for (int kk = 0; kk < 2; kk++) {
                #pragma unroll
                for (int mf = 0; mf < 4; mf++)
                    af[kk][mf] = *(const bf16x8*)((const char*)As +
                                   swz(wm * 64 + mf * 16 + lr, kk * 32 + lk));
                #pragma unroll
                for (int nf = 0; nf < 4; nf++)
                    bfr[kk][nf] = *(const bf16x8*)((const char*)Bs +
                                   swz(wn * 64 + nf * 16 + lr, kk * 32 + lk));
            }
            #pragma unroll
            for (int kk = 0; kk < 2; kk++)
                #pragma unroll
                for (int mf = 0; mf < 4; mf++)
                    #pragma unroll
                    for (int nf = 0; nf < 4; nf++)
                        acc[mf][nf] = __builtin_amdgcn_mfma_f32_16x16x32_bf16(
                            af[kk][mf], bfr[kk][nf], acc[mf][nf], 0, 0, 0);
            __syncthreads();
        }
        // ---- C write: per 16x16 frag row=(lane>>4)*4+reg, col=lane&15 ----
        int lr = lane & 15;
        #pragma unroll
        for (int mf = 0; mf < 4; mf++) {
            #pragma unroll
            for (int reg = 0; reg < 4; reg++) {
                int rl = wm * 64 + mf * 16 + (lane >> 4) * 4 + reg;
                if (rl < valid) {
                    size_t trow = (size_t)toks[rl] * DIM;
                    #pragma unroll
                    for (int nf = 0; nf < 4; nf++)
                        out[trow + n0 + wn * 64 + nf * 16 + lr] = acc[mf][nf][reg];
                }
            }
        }
    }
}

// ------------------------------------------------------------------
extern "C" void kernel_launch(void* const* d_in, const int* in_sizes, int n_in,
                              void* d_out, int out_size, void* d_ws, size_t ws_size,
                              hipStream_t stream) {
    const float* x  = (const float*)d_in[0];
    const float* gw = (const float*)d_in[1];
    const float* gb = (const float*)d_in[2];
    const float* ew = (const float*)d_in[3];
    float* out = (float*)d_out;
    char* ws = (char*)d_ws;
    int*    cnt   = (int*)(ws + WS_CNT);
    int*    ntile = (int*)(ws + WS_NTILE);
    int*    desc  = (int*)(ws + WS_DESC);
    int*    list  = (int*)(ws + WS_LIST);
    bf16_t* xbf   = (bf16_t*)(ws + WS_XBF);
    bf16_t* w2    = (bf16_t*)(ws + WS_W2);
    bool psum = (ws_size >= WS_NEED_PSUM);

    hipMemsetAsync(d_ws, 0, 4096, stream);
    route<<<dim3(2048), 256, 0, stream>>>(x, gw, gb, xbf, cnt, list);
    if (psum)
        sumw<<<dim3(16, 16, 28), 256, 0, stream>>>(ew, w2);
    else
        transpose_w<<<dim3(16, 16, 8), 256, 0, stream>>>(ew, w2);
    prep<<<dim3(1), 64, 0, stream>>>(cnt, ntile, desc);
    if (psum)
        moe_gemm<1><<<dim3(768), 256, 0, stream>>>(xbf, w2, cnt, ntile, desc, list, out);
    else
        moe_gemm<0><<<dim3(768), 256, 0, stream>>>(xbf, w2, cnt, ntile, desc, list, out);
}

// Round 3
// 146.280 us; speedup vs baseline: 1.2332x; 1.0584x over previous
//
#include <hip/hip_runtime.h>
#include <hip/hip_bf16.h>
#include <stdint.h>

#define T_TOK 8192
#define DIM   1024
#define NEXP  8
#define BM    128
#define BN    128
#define BK    64

typedef __bf16 bf16_t;
typedef bf16_t bf16x8 __attribute__((ext_vector_type(8)));
typedef bf16_t bf16x4 __attribute__((ext_vector_type(4)));
typedef float  f32x4  __attribute__((ext_vector_type(4)));

// ---- workspace layout (bytes) ----
#define WS_CNT    0                  // 64 ints (pair counters)
#define WS_LIST   4096               // 64 * 8192 ints = 2 MB
#define WS_XBF    (4u << 20)         // T*D bf16 = 16 MB
#define WS_W2     (20u << 20)        // WSUM (28*2MB=56MB) or fallback WT (16MB)
#define WS_NEED_PSUM ((size_t)76 << 20)

// pair index tables: pk -> (a,b), a<b
__device__ const int d_PA[28] = {0,0,0,0,0,0,0,1,1,1,1,1,1,2,2,2,2,2,3,3,3,3,4,4,4,5,5,6};
__device__ const int d_PB[28] = {1,2,3,4,5,6,7,2,3,4,5,6,7,3,4,5,6,7,4,5,6,7,5,6,7,6,7,7};

// async 16B global -> LDS (lds dest is wave-uniform base; HW adds lane*16)
__device__ __forceinline__ void gload16(const void* g, void* l) {
    __builtin_amdgcn_global_load_lds(
        (const __attribute__((address_space(1))) unsigned int*)g,
        (__attribute__((address_space(3))) unsigned int*)l, 16, 0, 0);
}

// swizzled byte offset within a [rows][BK] bf16 tile
__device__ __forceinline__ int swz(int r, int k) {
    return ((r * BK + k) * 2) ^ ((r & 7) << 4);
}

// ------------------------------------------------------------------
// sumw: WSUM[pk][f][d] = bf16(ew[a][d][f] + ew[b][d][f])   (28 pairs)
// ------------------------------------------------------------------
__global__ __launch_bounds__(256) void sumw(const float* __restrict__ ew,
                                            bf16_t* __restrict__ wsum) {
    __shared__ float tile[64][65];
    int pk = blockIdx.z;
    int a = d_PA[pk], b = d_PB[pk];
    int d0 = blockIdx.y * 64;
    int f0 = blockIdx.x * 64;
    int tid = threadIdx.x;
    const float* s1 = ew + ((size_t)a * DIM + d0) * DIM + f0;
    const float* s2 = ew + ((size_t)b * DIM + d0) * DIM + f0;
    int fl = (tid & 15) * 4;
    int dl = tid >> 4;
    #pragma unroll
    for (int i = 0; i < 4; i++) {
        int d = dl + i * 16;
        float4 u = *(const float4*)(s1 + (size_t)d * DIM + fl);
        float4 v = *(const float4*)(s2 + (size_t)d * DIM + fl);
        tile[d][fl + 0] = u.x + v.x; tile[d][fl + 1] = u.y + v.y;
        tile[d][fl + 2] = u.z + v.z; tile[d][fl + 3] = u.w + v.w;
    }
    __syncthreads();
    bf16_t* dst = wsum + ((size_t)pk * DIM + f0) * DIM + d0;
    int dl2 = (tid & 7) * 8;
    int fl2 = tid >> 3;          // 0..31
    #pragma unroll
    for (int i = 0; i < 2; i++) {
        int f = fl2 + i * 32;
        bf16x8 o;
        #pragma unroll
        for (int c = 0; c < 8; c++) o[c] = (bf16_t)tile[dl2 + c][f];
        *(bf16x8*)(dst + (size_t)f * DIM + dl2) = o;
    }
}

// ------------------------------------------------------------------
// fallback: WT[e][f][d] = bf16(expert_w[e][d][f])
// ------------------------------------------------------------------
__global__ __launch_bounds__(256) void transpose_w(const float* __restrict__ ew,
                                                   bf16_t* __restrict__ wt) {
    __shared__ float tile[64][65];
    int e  = blockIdx.z;
    int d0 = blockIdx.y * 64;
    int f0 = blockIdx.x * 64;
    int tid = threadIdx.x;
    const float* src = ew + ((size_t)e * DIM + d0) * DIM + f0;
    int fl = (tid & 15) * 4;
    int dl = tid >> 4;
    #pragma unroll
    for (int i = 0; i < 4; i++) {
        int d = dl + i * 16;
        float4 v = *(const float4*)(src + (size_t)d * DIM + fl);
        tile[d][fl + 0] = v.x; tile[d][fl + 1] = v.y;
        tile[d][fl + 2] = v.z; tile[d][fl + 3] = v.w;
    }
    __syncthreads();
    bf16_t* dst = wt + ((size_t)e * DIM + f0) * DIM + d0;
    int dl2 = (tid & 7) * 8;
    int fl2 = tid >> 3;
    #pragma unroll
    for (int i = 0; i < 2; i++) {
        int f = fl2 + i * 32;
        bf16x8 o;
        #pragma unroll
        for (int c = 0; c < 8; c++) o[c] = (bf16_t)tile[dl2 + c][f];
        *(bf16x8*)(dst + (size_t)f * DIM + dl2) = o;
    }
}

// ------------------------------------------------------------------
// route: gw transposed into LDS (coalesced), logits -> top2 -> bucket;
// x -> bf16 copy with 16B stores. 8 tokens/block (wave-per-token x2).
// ------------------------------------------------------------------
__global__ __launch_bounds__(256) void route(const float* __restrict__ x,
                                             const float* __restrict__ gw,
                                             const float* __restrict__ gb,
                                             bf16_t* __restrict__ xbf,
                                             int* __restrict__ cnt,
                                             int* __restrict__ list) {
    __shared__ float gwt[NEXP * DIM];          // 32 KB, [e][d]
    int tid = threadIdx.x;
    const float4* gw4 = (const float4*)gw;     // gw is [D][8] fp32
    #pragma unroll
    for (int i = 0; i < 8; i++) {
        int f4 = tid + i * 256;                // float4 index (2048 total)
        float4 v = gw4[f4];
        int d  = f4 >> 1;
        int e0 = (f4 & 1) * 4;
        gwt[(e0 + 0) * DIM + d] = v.x;
        gwt[(e0 + 1) * DIM + d] = v.y;
        gwt[(e0 + 2) * DIM + d] = v.z;
        gwt[(e0 + 3) * DIM + d] = v.w;
    }
    __syncthreads();
    int wid  = tid >> 6;
    int lane = tid & 63;
    for (int tt = 0; tt < 2; tt++) {
        int t = blockIdx.x * 8 + wid * 2 + tt;
        const float* xr = x + (size_t)t * DIM;
        float acc[NEXP] = {};
        #pragma unroll
        for (int j = 0; j < 2; j++) {
            int d = j * 512 + lane * 8;
            float4 v0 = *(const float4*)(xr + d);
            float4 v1 = *(const float4*)(xr + d + 4);
            bf16x8 b;
            b[0] = (bf16_t)v0.x; b[1] = (bf16_t)v0.y;
            b[2] = (bf16_t)v0.z; b[3] = (bf16_t)v0.w;
            b[4] = (bf16_t)v1.x; b[5] = (bf16_t)v1.y;
            b[6] = (bf16_t)v1.z; b[7] = (bf16_t)v1.w;
            *(bf16x8*)(xbf + (size_t)t * DIM + d) = b;
            #pragma unroll
            for (int e = 0; e < NEXP; e++) {
                const float* g = gwt + e * DIM + d;
                float4 g0 = *(const float4*)(g);
                float4 g1 = *(const float4*)(g + 4);
                acc[e] += v0.x * g0.x + v0.y * g0.y + v0.z * g0.z + v0.w * g0.w
                        + v1.x * g1.x + v1.y * g1.y + v1.z * g1.z + v1.w * g1.w;
            }
        }
        for (int off = 32; off >= 1; off >>= 1)
            #pragma unroll
            for (int e = 0; e < NEXP; e++)
                acc[e] += __shfl_xor(acc[e], off, 64);
        if (lane == 0) {
            float logit[NEXP];
            #pragma unroll
            for (int e = 0; e < NEXP; e++) logit[e] = acc[e] + gb[e];
            int b1 = 0; float best = logit[0];
            for (int e = 1; e < NEXP; e++) if (logit[e] > best) { best = logit[e]; b1 = e; }
            int b2 = -1; float best2 = -3.0e38f;
            for (int e = 0; e < NEXP; e++) {
                if (e == b1) continue;
                if (logit[e] > best2) { best2 = logit[e]; b2 = e; }
            }
            int a = min(b1, b2), bb = max(b1, b2);
            int p = a * 8 + bb;
            int pos = atomicAdd(&cnt[p], 1);
            list[p * T_TOK + pos] = t;
        }
    }
}

// ------------------------------------------------------------------
// grouped GEMM: per-block tile map (prep folded in), C[128x128]/item,
// BK=64, 4 waves (2x2). A gathered by token, B from WSUM[pk] (PSUM=1)
// or dual-WT reg-staged (PSUM=0). global_load_lds w/ pre-swizzled src.
// ------------------------------------------------------------------
template <int PSUM>
__global__ __launch_bounds__(256) void moe_gemm(const bf16_t* __restrict__ xbf,
                                                const bf16_t* __restrict__ wsrc,
                                                const int* __restrict__ cnt,
                                                const int* __restrict__ list,
                                                float* __restrict__ out) {
    __shared__ __align__(16) bf16_t As[BM * BK];
    __shared__ __align__(16) bf16_t Bs[BN * BK];
    __shared__ int toks[BM];
    __shared__ int s_desc[128];
    __shared__ int s_ntile;
    int tid  = threadIdx.x;
    int lane = tid & 63;
    int wv   = tid >> 6;
    int wm   = wv >> 1, wn = wv & 1;

    // ---- build tile map in-block (one wave) ----
    if (tid < 64) {
        int c  = cnt[tid];
        int tp = (c + BM - 1) >> 7;
        int pre = 0, tot = 0;
        for (int i = 0; i < 64; i++) {
            int v = __shfl(tp, i, 64);
            if (i < tid) pre += v;
            tot += v;
        }
        for (int j = 0; j < tp; j++)
            s_desc[pre + j] = tid | ((j * BM) << 8);
        if (tid == 0) s_ntile = tot;
    }
    __syncthreads();
    int nwork = s_ntile * (DIM / BN);

    for (int w = blockIdx.x; w < nwork; w += gridDim.x) {
        __syncthreads();                     // protect toks/LDS from prev item
        int dsc = s_desc[w >> 3];
        int n0  = (w & 7) * BN;
        int p   = dsc & 63;
        int m0  = dsc >> 8;
        int e1  = p >> 3, e2 = p & 7;
        int cp  = cnt[p];
        int valid = min(BM, cp - m0);
        if (tid < BM) toks[tid] = list[p * T_TOK + m0 + min(tid, valid - 1)];
        __syncthreads();

        // pre-swizzled gather sources (LDS dest stays linear)
        const bf16_t* asrc[4];
        #pragma unroll
        for (int i = 0; i < 4; i++) {
            int c = i * 256 + tid;
            int r = c >> 3, js = (c & 7) ^ (r & 7);
            asrc[i] = xbf + (size_t)toks[r] * DIM + js * 8;
        }
        const bf16_t* bsrc[4];
        const bf16_t *wt1 = nullptr, *wt2 = nullptr;
        if (PSUM) {
            int pk = e1 * 7 - (e1 * (e1 - 1)) / 2 + (e2 - e1 - 1);
            const bf16_t* bb = wsrc + (size_t)pk * DIM * DIM;
            #pragma unroll
            for (int i = 0; i < 4; i++) {
                int c = i * 256 + tid;
                int r = c >> 3, js = (c & 7) ^ (r & 7);
                bsrc[i] = bb + (size_t)(n0 + r) * DIM + js * 8;
            }
        } else {
            wt1 = wsrc + (size_t)e1 * DIM * DIM;
            wt2 = wsrc + (size_t)e2 * DIM * DIM;
        }

        f32x4 acc[4][4] = {};
        for (int k0 = 0; k0 < DIM; k0 += BK) {
            #pragma unroll
            for (int i = 0; i < 4; i++)
                gload16(asrc[i] + k0, As + (size_t)(i * 256 + wv * 64) * 8);
            if (PSUM) {
                #pragma unroll
                for (int i = 0; i < 4; i++)
                    gload16(bsrc[i] + k0, Bs + (size_t)(i * 256 + wv * 64) * 8);
            } else {
                #pragma unroll
                for (int fo = 0; fo < 2; fo++) {
                    int f = fo * 64 + (tid >> 2), q = tid & 3;
                    const bf16_t* s1 = wt1 + (size_t)(n0 + f) * DIM + k0 + q * 16;
                    const bf16_t* s2 = wt2 + (size_t)(n0 + f) * DIM + k0 + q * 16;
                    bf16x8 u0 = *(const bf16x8*)s1;
                    bf16x8 u1 = *(const bf16x8*)(s1 + 8);
                    bf16x8 w0 = *(const bf16x8*)s2;
                    bf16x8 w1 = *(const bf16x8*)(s2 + 8);
                    bf16x8 o0, o1;
                    #pragma unroll
                    for (int i = 0; i < 8; i++) {
                        o0[i] = (bf16_t)((float)u0[i] + (float)w0[i]);
                        o1[i] = (bf16_t)((float)u1[i] + (float)w1[i]);
                    }
                    *(bf16x8*)((char*)Bs + swz(f, q * 16))     = o0;
                    *(bf16x8*)((char*)Bs + swz(f, q * 16 + 8)) = o1;
                }
            }
            __syncthreads();                 // drains vmcnt+lgkmcnt
            int lr = lane & 15;
            int lk = (lane >> 4) * 8;
            bf16x8 af[2][4], bfr[2][4];
            #pragma unroll
            for (int kk = 0; kk < 2; kk++) {
                #pragma unroll
                for (int mf = 0; mf < 4; mf++)
                    af[kk][mf] = *(const bf16x8*)((const char*)As +
                                   swz(wm * 64 + mf * 16 + lr, kk * 32 + lk));
                #pragma unroll
                for (int nf = 0; nf < 4; nf++)
                    bfr[kk][nf] = *(const bf16x8*)((const char*)Bs +
                                   swz(wn * 64 + nf * 16 + lr, kk * 32 + lk));
            }
            #pragma unroll
            for (int kk = 0; kk < 2; kk++)
                #pragma unroll
                for (int mf = 0; mf < 4; mf++)
                    #pragma unroll
                    for (int nf = 0; nf < 4; nf++)
                        acc[mf][nf] = __builtin_amdgcn_mfma_f32_16x16x32_bf16(
                            af[kk][mf], bfr[kk][nf], acc[mf][nf], 0, 0, 0);
            __syncthreads();
        }
        int lr = lane & 15;
        #pragma unroll
        for (int mf = 0; mf < 4; mf++) {
            #pragma unroll
            for (int reg = 0; reg < 4; reg++) {
                int rl = wm * 64 + mf * 16 + (lane >> 4) * 4 + reg;
                if (rl < valid) {
                    size_t trow = (size_t)toks[rl] * DIM;
                    #pragma unroll
                    for (int nf = 0; nf < 4; nf++)
                        out[trow + n0 + wn * 64 + nf * 16 + lr] = acc[mf][nf][reg];
                }
            }
        }
    }
}

// ------------------------------------------------------------------
extern "C" void kernel_launch(void* const* d_in, const int* in_sizes, int n_in,
                              void* d_out, int out_size, void* d_ws, size_t ws_size,
                              hipStream_t stream) {
    const float* x  = (const float*)d_in[0];
    const float* gw = (const float*)d_in[1];
    const float* gb = (const float*)d_in[2];
    const float* ew = (const float*)d_in[3];
    float* out = (float*)d_out;
    char* ws = (char*)d_ws;
    int*    cnt  = (int*)(ws + WS_CNT);
    int*    list = (int*)(ws + WS_LIST);
    bf16_t* xbf  = (bf16_t*)(ws + WS_XBF);
    bf16_t* w2   = (bf16_t*)(ws + WS_W2);
    bool psum = (ws_size >= WS_NEED_PSUM);

    hipMemsetAsync(d_ws, 0, 4096, stream);
    route<<<dim3(1024), 256, 0, stream>>>(x, gw, gb, xbf, cnt, list);
    if (psum)
        sumw<<<dim3(16, 16, 28), 256, 0, stream>>>(ew, w2);
    else
        transpose_w<<<dim3(16, 16, 8), 256, 0, stream>>>(ew, w2);
    if (psum)
        moe_gemm<1><<<dim3(768), 256, 0, stream>>>(xbf, w2, cnt, list, out);
    else
        moe_gemm<0><<<dim3(768), 256, 0, stream>>>(xbf, w2, cnt, list, out);
}

// Round 4
// 130.596 us; speedup vs baseline: 1.3813x; 1.1201x over previous
//
#include <hip/hip_runtime.h>
#include <hip/hip_bf16.h>
#include <stdint.h>

#define T_TOK 8192
#define DIM   1024
#define NEXP  8
#define BM    128
#define BN    128
#define BK    64

typedef __bf16 bf16_t;
typedef bf16_t bf16x8 __attribute__((ext_vector_type(8)));
typedef float  f32x4  __attribute__((ext_vector_type(4)));

// ---- workspace layout (bytes) ----
#define WS_CNT    0                  // 64 ints (pair counters)
#define WS_LIST   4096               // 64 * 8192 ints = 2 MB
#define WS_XBF    (4u << 20)         // T*D bf16 = 16 MB
#define WS_W2     (20u << 20)        // WSUM (28*2MB=56MB) or fallback WT (16MB)
#define WS_NEED_PSUM ((size_t)76 << 20)

// pair index tables: pk -> (a,b), a<b
__device__ const int d_PA[28] = {0,0,0,0,0,0,0,1,1,1,1,1,1,2,2,2,2,2,3,3,3,3,4,4,4,5,5,6};
__device__ const int d_PB[28] = {1,2,3,4,5,6,7,2,3,4,5,6,7,3,4,5,6,7,4,5,6,7,5,6,7,6,7,7};

// async 16B global -> LDS (lds dest is wave-uniform base; HW adds lane*16)
__device__ __forceinline__ void gload16(const void* g, void* l) {
    __builtin_amdgcn_global_load_lds(
        (const __attribute__((address_space(1))) unsigned int*)g,
        (__attribute__((address_space(3))) unsigned int*)l, 16, 0, 0);
}

// swizzled byte offset within a [rows][BK] bf16 tile
__device__ __forceinline__ int swz(int r, int k) {
    return ((r * BK + k) * 2) ^ ((r & 7) << 4);
}

#define WAITCNT_VM0()   do { asm volatile("s_waitcnt vmcnt(0)" ::: "memory"); \
                             __builtin_amdgcn_sched_barrier(0); } while (0)
#define WAITCNT_LGKM0() do { asm volatile("s_waitcnt lgkmcnt(0)" ::: "memory"); \
                             __builtin_amdgcn_sched_barrier(0); } while (0)
#define BARRIER()       do { __builtin_amdgcn_s_barrier(); \
                             __builtin_amdgcn_sched_barrier(0); } while (0)

// ------------------------------------------------------------------
// fused_pre: blocks [0,1024) = route; blocks [1024,...) = sumw (PSUM)
// or transpose_w (fallback). Independent work overlapped in one dispatch.
// ------------------------------------------------------------------
template <int PSUM>
__global__ __launch_bounds__(256) void fused_pre(const float* __restrict__ x,
                                                 const float* __restrict__ gw,
                                                 const float* __restrict__ gb,
                                                 const float* __restrict__ ew,
                                                 bf16_t* __restrict__ xbf,
                                                 bf16_t* __restrict__ w2,
                                                 int* __restrict__ cnt,
                                                 int* __restrict__ list) {
    __shared__ __align__(16) float sh[NEXP * DIM];   // 32 KB, shared by both roles
    int bx  = blockIdx.x;
    int tid = threadIdx.x;
    if (bx < 1024) {
        // ---------------- route ----------------
        float* gwt = sh;                       // [e][d]
        const float4* gw4 = (const float4*)gw; // gw is [D][8] fp32
        #pragma unroll
        for (int i = 0; i < 8; i++) {
            int f4 = tid + i * 256;
            float4 v = gw4[f4];
            int d  = f4 >> 1;
            int e0 = (f4 & 1) * 4;
            gwt[(e0 + 0) * DIM + d] = v.x;
            gwt[(e0 + 1) * DIM + d] = v.y;
            gwt[(e0 + 2) * DIM + d] = v.z;
            gwt[(e0 + 3) * DIM + d] = v.w;
        }
        __syncthreads();
        int wid  = tid >> 6;
        int lane = tid & 63;
        for (int tt = 0; tt < 2; tt++) {
            int t = bx * 8 + wid * 2 + tt;
            const float* xr = x + (size_t)t * DIM;
            float acc[NEXP] = {};
            #pragma unroll
            for (int j = 0; j < 2; j++) {
                int d = j * 512 + lane * 8;
                float4 v0 = *(const float4*)(xr + d);
                float4 v1 = *(const float4*)(xr + d + 4);
                bf16x8 b;
                b[0] = (bf16_t)v0.x; b[1] = (bf16_t)v0.y;
                b[2] = (bf16_t)v0.z; b[3] = (bf16_t)v0.w;
                b[4] = (bf16_t)v1.x; b[5] = (bf16_t)v1.y;
                b[6] = (bf16_t)v1.z; b[7] = (bf16_t)v1.w;
                *(bf16x8*)(xbf + (size_t)t * DIM + d) = b;
                #pragma unroll
                for (int e = 0; e < NEXP; e++) {
                    const float* g = gwt + e * DIM + d;
                    float4 g0 = *(const float4*)(g);
                    float4 g1 = *(const float4*)(g + 4);
                    acc[e] += v0.x * g0.x + v0.y * g0.y + v0.z * g0.z + v0.w * g0.w
                            + v1.x * g1.x + v1.y * g1.y + v1.z * g1.z + v1.w * g1.w;
                }
            }
            for (int off = 32; off >= 1; off >>= 1)
                #pragma unroll
                for (int e = 0; e < NEXP; e++)
                    acc[e] += __shfl_xor(acc[e], off, 64);
            if (lane == 0) {
                float logit[NEXP];
                #pragma unroll
                for (int e = 0; e < NEXP; e++) logit[e] = acc[e] + gb[e];
                int b1 = 0; float best = logit[0];
                for (int e = 1; e < NEXP; e++) if (logit[e] > best) { best = logit[e]; b1 = e; }
                int b2 = -1; float best2 = -3.0e38f;
                for (int e = 0; e < NEXP; e++) {
                    if (e == b1) continue;
                    if (logit[e] > best2) { best2 = logit[e]; b2 = e; }
                }
                int a = min(b1, b2), bb = max(b1, b2);
                int p = a * 8 + bb;
                int pos = atomicAdd(&cnt[p], 1);
                list[p * T_TOK + pos] = t;
            }
        }
    } else {
        // ---------------- sumw / transpose_w ----------------
        int bz  = bx - 1024;
        int g   = bz >> 8;                 // pk (PSUM) or expert e
        int rem = bz & 255;
        int f0  = (rem & 15) * 64;
        int d0  = (rem >> 4) * 64;
        float (*tile)[65] = (float (*)[65])sh;
        int a = PSUM ? d_PA[g] : g;
        int b = PSUM ? d_PB[g] : g;
        const float* s1 = ew + ((size_t)a * DIM + d0) * DIM + f0;
        const float* s2 = ew + ((size_t)b * DIM + d0) * DIM + f0;
        int fl = (tid & 15) * 4;
        int dl = tid >> 4;
        #pragma unroll
        for (int i = 0; i < 4; i++) {
            int d = dl + i * 16;
            float4 u = *(const float4*)(s1 + (size_t)d * DIM + fl);
            if (PSUM) {
                float4 v = *(const float4*)(s2 + (size_t)d * DIM + fl);
                u.x += v.x; u.y += v.y; u.z += v.z; u.w += v.w;
            }
            tile[d][fl + 0] = u.x; tile[d][fl + 1] = u.y;
            tile[d][fl + 2] = u.z; tile[d][fl + 3] = u.w;
        }
        __syncthreads();
        bf16_t* dst = w2 + ((size_t)g * DIM + f0) * DIM + d0;
        int dl2 = (tid & 7) * 8;
        int fl2 = tid >> 3;
        #pragma unroll
        for (int i = 0; i < 2; i++) {
            int f = fl2 + i * 32;
            bf16x8 o;
            #pragma unroll
            for (int c = 0; c < 8; c++) o[c] = (bf16_t)tile[dl2 + c][f];
            *(bf16x8*)(dst + (size_t)f * DIM + dl2) = o;
        }
    }
}

// ------------------------------------------------------------------
// grouped GEMM: per-block tile map, C[128x128]/item, BK=64, 4 waves.
// 2-phase double-buffered pipeline: stage(k+1) issued before compute(k);
// one vmcnt(0)+s_barrier per K-step. XCD-chunked item mapping for L2.
// ------------------------------------------------------------------
template <int PSUM>
__global__ __launch_bounds__(256, 2) void moe_gemm(const bf16_t* __restrict__ xbf,
                                                   const bf16_t* __restrict__ wsrc,
                                                   const int* __restrict__ cnt,
                                                   const int* __restrict__ list,
                                                   float* __restrict__ out) {
    __shared__ __align__(16) bf16_t As[2][BM * BK];
    __shared__ __align__(16) bf16_t Bs[2][BN * BK];
    __shared__ int toks[BM];
    __shared__ int s_desc[128];
    __shared__ int s_ntile;
    int tid  = threadIdx.x;
    int lane = tid & 63;
    int wv   = tid >> 6;
    int wm   = wv >> 1, wn = wv & 1;

    // ---- build tile map in-block (one wave) ----
    if (tid < 64) {
        int c  = cnt[tid];
        int tp = (c + BM - 1) >> 7;
        int pre = 0, tot = 0;
        for (int i = 0; i < 64; i++) {
            int v = __shfl(tp, i, 64);
            if (i < tid) pre += v;
            tot += v;
        }
        for (int j = 0; j < tp; j++)
            s_desc[pre + j] = tid | ((j * BM) << 8);
        if (tid == 0) s_ntile = tot;
    }
    __syncthreads();
    int nwork = s_ntile * (DIM / BN);
    // XCD-chunked virtual block id: XCD j (blocks b%8==j) owns contiguous items
    int vb = ((blockIdx.x & 7) << 6) | (blockIdx.x >> 3);

    for (int wi = 0; wi < 2; wi++) {
        int w = vb * 2 + wi;
        if (w >= nwork) break;
        __syncthreads();                     // protect toks from prev item's readers
        int dsc = s_desc[w >> 3];
        int n0  = (w & 7) * BN;
        int p   = dsc & 63;
        int m0  = dsc >> 8;
        int e1  = p >> 3, e2 = p & 7;
        int cp  = cnt[p];
        int valid = min(BM, cp - m0);
        if (tid < BM) toks[tid] = list[p * T_TOK + m0 + min(tid, valid - 1)];
        __syncthreads();

        // pre-swizzled gather sources (LDS dest stays linear)
        const bf16_t* asrc[4];
        #pragma unroll
        for (int i = 0; i < 4; i++) {
            int c = i * 256 + tid;
            int r = c >> 3, js = (c & 7) ^ (r & 7);
            asrc[i] = xbf + (size_t)toks[r] * DIM + js * 8;
        }
        const bf16_t* bsrc[4];
        const bf16_t *wt1 = nullptr, *wt2 = nullptr;
        if (PSUM) {
            int pk = e1 * 7 - (e1 * (e1 - 1)) / 2 + (e2 - e1 - 1);
            const bf16_t* bb = wsrc + (size_t)pk * DIM * DIM;
            #pragma unroll
            for (int i = 0; i < 4; i++) {
                int c = i * 256 + tid;
                int r = c >> 3, js = (c & 7) ^ (r & 7);
                bsrc[i] = bb + (size_t)(n0 + r) * DIM + js * 8;
            }
        } else {
            wt1 = wsrc + (size_t)e1 * DIM * DIM;
            wt2 = wsrc + (size_t)e2 * DIM * DIM;
        }

        f32x4 acc[4][4] = {};
        int lr = lane & 15;
        int lk = (lane >> 4) * 8;

        // ---- prologue: stage K-tile 0 into buffer 0 ----
        #pragma unroll
        for (int i = 0; i < 4; i++)
            gload16(asrc[i], &As[0][(i * 256 + wv * 64) * 8]);
        if (PSUM) {
            #pragma unroll
            for (int i = 0; i < 4; i++)
                gload16(bsrc[i], &Bs[0][(i * 256 + wv * 64) * 8]);
        } else {
            #pragma unroll
            for (int fo = 0; fo < 2; fo++) {
                int f = fo * 64 + (tid >> 2), q = tid & 3;
                const bf16_t* s1 = wt1 + (size_t)(n0 + f) * DIM + q * 16;
                const bf16_t* s2 = wt2 + (size_t)(n0 + f) * DIM + q * 16;
                bf16x8 u0 = *(const bf16x8*)s1, u1 = *(const bf16x8*)(s1 + 8);
                bf16x8 w0 = *(const bf16x8*)s2, w1 = *(const bf16x8*)(s2 + 8);
                bf16x8 o0, o1;
                #pragma unroll
                for (int i = 0; i < 8; i++) {
                    o0[i] = (bf16_t)((float)u0[i] + (float)w0[i]);
                    o1[i] = (bf16_t)((float)u1[i] + (float)w1[i]);
                }
                *(bf16x8*)((char*)Bs[0] + swz(f, q * 16))     = o0;
                *(bf16x8*)((char*)Bs[0] + swz(f, q * 16 + 8)) = o1;
            }
            WAITCNT_LGKM0();
        }
        WAITCNT_VM0();
        BARRIER();

        int cur = 0;
        for (int ks = 0; ks < DIM / BK; ks++) {
            // ---- issue stage of K-tile ks+1 into buffer cur^1 ----
            if (ks < DIM / BK - 1) {
                int k1 = (ks + 1) * BK;
                #pragma unroll
                for (int i = 0; i < 4; i++)
                    gload16(asrc[i] + k1, &As[cur ^ 1][(i * 256 + wv * 64) * 8]);
                if (PSUM) {
                    #pragma unroll
                    for (int i = 0; i < 4; i++)
                        gload16(bsrc[i] + k1, &Bs[cur ^ 1][(i * 256 + wv * 64) * 8]);
                } else {
                    #pragma unroll
                    for (int fo = 0; fo < 2; fo++) {
                        int f = fo * 64 + (tid >> 2), q = tid & 3;
                        const bf16_t* s1 = wt1 + (size_t)(n0 + f) * DIM + k1 + q * 16;
                        const bf16_t* s2 = wt2 + (size_t)(n0 + f) * DIM + k1 + q * 16;
                        bf16x8 u0 = *(const bf16x8*)s1, u1 = *(const bf16x8*)(s1 + 8);
                        bf16x8 w0 = *(const bf16x8*)s2, w1 = *(const bf16x8*)(s2 + 8);
                        bf16x8 o0, o1;
                        #pragma unroll
                        for (int i = 0; i < 8; i++) {
                            o0[i] = (bf16_t)((float)u0[i] + (float)w0[i]);
                            o1[i] = (bf16_t)((float)u1[i] + (float)w1[i]);
                        }
                        *(bf16x8*)((char*)Bs[cur ^ 1] + swz(f, q * 16))     = o0;
                        *(bf16x8*)((char*)Bs[cur ^ 1] + swz(f, q * 16 + 8)) = o1;
                    }
                }
            }
            // ---- compute on buffer cur ----
            const char* Ab = (const char*)As[cur];
            const char* Bb = (const char*)Bs[cur];
            bf16x8 af[2][4], bfr[2][4];
            #pragma unroll
            for (int kk = 0; kk < 2; kk++) {
                #pragma unroll
                for (int mf = 0; mf < 4; mf++)
                    af[kk][mf] = *(const bf16x8*)(Ab + swz(wm * 64 + mf * 16 + lr, kk * 32 + lk));
                #pragma unroll
                for (int nf = 0; nf < 4; nf++)
                    bfr[kk][nf] = *(const bf16x8*)(Bb + swz(wn * 64 + nf * 16 + lr, kk * 32 + lk));
            }
            #pragma unroll
            for (int kk = 0; kk < 2; kk++)
                #pragma unroll
                for (int mf = 0; mf < 4; mf++)
                    #pragma unroll
                    for (int nf = 0; nf < 4; nf++)
                        acc[mf][nf] = __builtin_amdgcn_mfma_f32_16x16x32_bf16(
                            af[kk][mf], bfr[kk][nf], acc[mf][nf], 0, 0, 0);
            // ---- one wait+barrier per step: next buffer ready, this one free ----
            if (!PSUM) WAITCNT_LGKM0();
            WAITCNT_VM0();
            BARRIER();
            cur ^= 1;
        }

        // ---- C write: per 16x16 frag row=(lane>>4)*4+reg, col=lane&15 ----
        #pragma unroll
        for (int mf = 0; mf < 4; mf++) {
            #pragma unroll
            for (int reg = 0; reg < 4; reg++) {
                int rl = wm * 64 + mf * 16 + (lane >> 4) * 4 + reg;
                if (rl < valid) {
                    size_t trow = (size_t)toks[rl] * DIM;
                    #pragma unroll
                    for (int nf = 0; nf < 4; nf++)
                        out[trow + n0 + wn * 64 + nf * 16 + lr] = acc[mf][nf][reg];
                }
            }
        }
    }
}

// ------------------------------------------------------------------
extern "C" void kernel_launch(void* const* d_in, const int* in_sizes, int n_in,
                              void* d_out, int out_size, void* d_ws, size_t ws_size,
                              hipStream_t stream) {
    const float* x  = (const float*)d_in[0];
    const float* gw = (const float*)d_in[1];
    const float* gb = (const float*)d_in[2];
    const float* ew = (const float*)d_in[3];
    float* out = (float*)d_out;
    char* ws = (char*)d_ws;
    int*    cnt  = (int*)(ws + WS_CNT);
    int*    list = (int*)(ws + WS_LIST);
    bf16_t* xbf  = (bf16_t*)(ws + WS_XBF);
    bf16_t* w2   = (bf16_t*)(ws + WS_W2);
    bool psum = (ws_size >= WS_NEED_PSUM);

    hipMemsetAsync(d_ws, 0, 4096, stream);
    if (psum) {
        fused_pre<1><<<dim3(1024 + 28 * 256), 256, 0, stream>>>(x, gw, gb, ew, xbf, w2, cnt, list);
        moe_gemm<1><<<dim3(512), 256, 0, stream>>>(xbf, w2, cnt, list, out);
    } else {
        fused_pre<0><<<dim3(1024 + 8 * 256), 256, 0, stream>>>(x, gw, gb, ew, xbf, w2, cnt, list);
        moe_gemm<0><<<dim3(512), 256, 0, stream>>>(xbf, w2, cnt, list, out);
    }
}